// Round 3
// baseline (161.391 us; speedup 1.0000x reference)
//
#include <hip/hip_runtime.h>

// MetricBiasUpdater: B_next = clip(alpha*B_prev - beta*relu(pairdist(H@W^T)), -10, 10)
// B=4, N=2048, D=1024, K(geom)=32. Output fp32 [4,2048,2048].
//
// v4:
//  k0: W fp32 -> bf16 once.
//  k1: unchanged from v3 (LDS-staged H, MFMA, ~6 us on paper).
//  k2: barrier-free / LDS-free. G fragment loads go straight from global
//      (a 16-row x 16B frag is a contiguous 1KB region of G -> L2-hot).
//      Each wave: 8x Bp dwordx4 -> 9x G frag loads -> 8x MFMA -> epilogue.
//      No __syncthreads, no vmcnt(0) convoy; occupancy bound by VGPR only.

typedef __attribute__((ext_vector_type(8))) short short8;   // 8 bf16 (4 VGPRs)
typedef __attribute__((ext_vector_type(4))) short short4v;  // 4 bf16 (2 VGPRs)
typedef __attribute__((ext_vector_type(4))) float floatx4;  // MFMA acc

static __device__ __forceinline__ short bf16_bits(float f) {
    union { float f; unsigned int u; } v; v.f = f;
    unsigned int u = v.u;
    u += 0x7FFFu + ((u >> 16) & 1u);   // round-to-nearest-even
    return (short)(u >> 16);
}

static __device__ __forceinline__ float bf16_to_f32(unsigned short h) {
    union { unsigned int u; float f; } v; v.u = ((unsigned int)h) << 16;
    return v.f;
}

// ---------------------------------------------------------------------------
// Kernel 0: W fp32 [32][1024] -> bf16.
// ---------------------------------------------------------------------------
__global__ __launch_bounds__(256) void k0_wcast(const float* __restrict__ W,
                                                short* __restrict__ Wb) {
    const int f = blockIdx.x * 256 + threadIdx.x;   // 8192 float4 chunks
    const float4 v = *(const float4*)(W + (long)f * 4);
    short4v s;
    s[0] = bf16_bits(v.x); s[1] = bf16_bits(v.y);
    s[2] = bf16_bits(v.z); s[3] = bf16_bits(v.w);
    *(short4v*)(Wb + (long)f * 4) = s;
}

// ---------------------------------------------------------------------------
// Kernel 1: G[row][k] = sum_d H[row][d] * W[k][d]  (rows = 8192 flat, k = 32)
// One block = one 16-row m-tile. Stage H tile to LDS (coalesced), 4 waves
// each take a K-quarter (256), 8 MFMA steps of K=32, two n-tiles.
// LDS-reduce the 4 partials, round to bf16, write G and Q = rowsum(G^2).
// ---------------------------------------------------------------------------
__global__ __launch_bounds__(256) void k1_proj(const float* __restrict__ H,
                                               const short* __restrict__ Wb,
                                               unsigned short* __restrict__ G,
                                               float* __restrict__ Q) {
    const int blk  = blockIdx.x;        // 512 blocks x 16 rows
    const int t    = threadIdx.x;
    const int w    = t >> 6;            // wave id -> K quarter
    const int lane = t & 63;
    const int m    = lane & 15;         // A row within tile / B column n
    const int quad = lane >> 4;

    __shared__ short sH[16 * 1032];     // 16 rows x 1024 bf16, stride 1032 (33 KB)

    // ---- coalesced stage: 2048 8-float chunks, 8 per thread ----
    const float* Hb = H + (long)blk * 16384;
    #pragma unroll
    for (int it = 0; it < 8; ++it) {
        const int f  = t + it * 256;    // 0..2047
        const int r  = f >> 7;          // row 0..15
        const int c8 = f & 127;         // 8-float chunk within row
        const float4 v0 = *(const float4*)(Hb + r * 1024 + c8 * 8);
        const float4 v1 = *(const float4*)(Hb + r * 1024 + c8 * 8 + 4);
        short8 sv;
        sv[0] = bf16_bits(v0.x); sv[1] = bf16_bits(v0.y);
        sv[2] = bf16_bits(v0.z); sv[3] = bf16_bits(v0.w);
        sv[4] = bf16_bits(v1.x); sv[5] = bf16_bits(v1.y);
        sv[6] = bf16_bits(v1.z); sv[7] = bf16_bits(v1.w);
        *(short8*)&sH[r * 1032 + c8 * 8] = sv;
    }
    __syncthreads();

    const int kq = w * 256 + quad * 8;  // this lane's k base (frag: k = quad*8 + j)
    const short* wb0 = Wb + (long)m * 1024 + kq;          // n-tile 0: n = m
    const short* wb1 = Wb + (long)(m + 16) * 1024 + kq;   // n-tile 1: n = m+16

    floatx4 acc0 = {0.f, 0.f, 0.f, 0.f};
    floatx4 acc1 = {0.f, 0.f, 0.f, 0.f};

    short8 b0 = *(const short8*)wb0;
    short8 b1 = *(const short8*)wb1;

    #pragma unroll
    for (int s = 0; s < 8; ++s) {
        short8 nb0, nb1;
        if (s < 7) {                    // prefetch next W-step while MFMA runs
            nb0 = *(const short8*)(wb0 + (s + 1) * 32);
            nb1 = *(const short8*)(wb1 + (s + 1) * 32);
        }
        const short8 af = *(const short8*)&sH[m * 1032 + kq + s * 32];
        acc0 = __builtin_amdgcn_mfma_f32_16x16x32_bf16(af, b0, acc0, 0, 0, 0);
        acc1 = __builtin_amdgcn_mfma_f32_16x16x32_bf16(af, b1, acc1, 0, 0, 0);
        if (s < 7) { b0 = nb0; b1 = nb1; }
    }

    // reduce K-quarter partials across the 4 waves.
    // C/D layout: col = lane&15 (=n), row = quad*4 + reg (=m)  (measured m89)
    __shared__ float red[4][16][32];
    #pragma unroll
    for (int r = 0; r < 4; ++r) {
        red[w][quad * 4 + r][m]      = acc0[r];
        red[w][quad * 4 + r][m + 16] = acc1[r];
    }
    __syncthreads();
    for (int e = t; e < 512; e += 256) {
        const int mm = e >> 5, nn = e & 31;
        float v = red[0][mm][nn] + red[1][mm][nn] + red[2][mm][nn] + red[3][mm][nn];
        const unsigned short hb = (unsigned short)bf16_bits(v);
        G[(long)(blk * 16 + mm) * 32 + nn] = hb;
        red[0][mm][nn] = bf16_to_f32(hb);   // Q from ROUNDED values: dist(i,i) ~ 0
    }
    __syncthreads();
    if (t < 16) {
        float s = 0.f;
        #pragma unroll
        for (int nn = 0; nn < 32; ++nn) { const float v = red[0][t][nn]; s += v * v; }
        Q[blk * 16 + t] = s;
    }
}

// ---------------------------------------------------------------------------
// Kernel 2: out[b][i][j] = clip(alpha*Bp - beta*relu(q[i]+q[j]-2*G[i].G[j]))
// 64(i) x 128(j) tile per block, 4 waves, NO LDS, NO barriers.
// Wave owns 16 i-rows. G frags loaded directly from global:
//   frag for 16 rows x 16B = contiguous 1KB of G (rows are 64B) -> L2-hot.
// mfma(Gj_frag, Gi_frag): D row = quad*4+r = j (consecutive), col = m = i.
// Epilogue: 8x dwordx4 Bp (issued first) + 8x dwordx4 stores, 64B segments.
// ---------------------------------------------------------------------------
__global__ __launch_bounds__(256, 4) void k2_update(const float* __restrict__ Bp,
                                                    const unsigned short* __restrict__ G,
                                                    const float* __restrict__ Q,
                                                    const float* __restrict__ alphap,
                                                    const float* __restrict__ betap,
                                                    float* __restrict__ out) {
    const int b  = blockIdx.z;
    const int i0 = blockIdx.y * 64;
    const int j0 = blockIdx.x * 128;
    const int t  = threadIdx.x;
    const int w    = t >> 6;          // wave -> i rows [w*16, w*16+16)
    const int lane = t & 63;
    const int m    = lane & 15;       // i within wave tile (D column)
    const int quad = lane >> 4;       // j sub-quad (D row group)

    // ---- issue all Bp loads first (longest latency, HBM) ----
    const int i = i0 + w * 16 + m;
    const long rowoff = ((long)b * 2048 + i) * 2048 + j0;
    const float4* bp4 = (const float4*)(Bp + rowoff);
    float4 bv[8];
    #pragma unroll
    for (int jt = 0; jt < 8; ++jt) bv[jt] = bp4[jt * 4 + quad];  // j = jt*16+quad*4

    // ---- G fragments straight from global (L2/L3-resident, 512 KB total) ----
    const short* Gg = (const short*)G;
    // B-frag (index = i): lane holds Gi row w*16+m, bytes [quad*16, quad*16+16)
    const short8 bfi = *(const short8*)&Gg[((long)(b * 2048 + i0 + w * 16 + m)) * 32 + quad * 8];
    // A-frags (index = j): lane holds Gj row jt*16+m, same k slice
    short8 afj[8];
    const long gj_base = ((long)(b * 2048 + j0 + m)) * 32 + quad * 8;
    #pragma unroll
    for (int jt = 0; jt < 8; ++jt)
        afj[jt] = *(const short8*)&Gg[gj_base + (long)jt * 16 * 32];

    const float qi = Q[b * 2048 + i];

    floatx4 acc[8];
    #pragma unroll
    for (int jt = 0; jt < 8; ++jt) {
        floatx4 z = {0.f, 0.f, 0.f, 0.f};
        acc[jt] = __builtin_amdgcn_mfma_f32_16x16x32_bf16(afj[jt], bfi, z, 0, 0, 0);
    }

    const float alpha = alphap[0];
    const float beta  = betap[0];
    float4* o4 = (float4*)(out + rowoff);

    #pragma unroll
    for (int jt = 0; jt < 8; ++jt) {
        // D layout: row = quad*4 + r = j within tile jt, col = m = i
        const float4 qjv = *(const float4*)&Q[b * 2048 + j0 + jt * 16 + quad * 4];
        const float4 bvv = bv[jt];
        float4 ov;
        {
            float d = qi + qjv.x - 2.f * acc[jt][0];
            d = fmaxf(d, 0.f);
            ov.x = fminf(fmaxf(alpha * bvv.x - beta * d, -10.f), 10.f);
        }
        {
            float d = qi + qjv.y - 2.f * acc[jt][1];
            d = fmaxf(d, 0.f);
            ov.y = fminf(fmaxf(alpha * bvv.y - beta * d, -10.f), 10.f);
        }
        {
            float d = qi + qjv.z - 2.f * acc[jt][2];
            d = fmaxf(d, 0.f);
            ov.z = fminf(fmaxf(alpha * bvv.z - beta * d, -10.f), 10.f);
        }
        {
            float d = qi + qjv.w - 2.f * acc[jt][3];
            d = fmaxf(d, 0.f);
            ov.w = fminf(fmaxf(alpha * bvv.w - beta * d, -10.f), 10.f);
        }
        o4[jt * 4 + quad] = ov;
    }
}

extern "C" void kernel_launch(void* const* d_in, const int* in_sizes, int n_in,
                              void* d_out, int out_size, void* d_ws, size_t ws_size,
                              hipStream_t stream) {
    const float* H     = (const float*)d_in[0];   // [4,2048,1024]
    const float* Bp    = (const float*)d_in[1];   // [4,2048,2048]
    const float* W     = (const float*)d_in[2];   // [32,1024]
    const float* alpha = (const float*)d_in[3];
    const float* beta  = (const float*)d_in[4];
    float* out = (float*)d_out;

    unsigned short* G = (unsigned short*)d_ws;          // [8192][32] bf16 = 512 KB
    float* Q  = (float*)((char*)d_ws + 8192 * 32 * 2);  // [8192] fp32 = 32 KB
    short* Wb = (short*)((char*)d_ws + 8192 * 32 * 2 + 8192 * 4);  // [32][1024] bf16

    k0_wcast<<<32, 256, 0, stream>>>(W, Wb);
    k1_proj<<<512, 256, 0, stream>>>(H, Wb, G, Q);

    dim3 g2(16, 32, 4);               // j-tiles(128), i-tiles(64), batch
    k2_update<<<g2, 256, 0, stream>>>(Bp, G, Q, alpha, beta, out);
}

// Round 4
// 156.937 us; speedup vs baseline: 1.0284x; 1.0284x over previous
//
#include <hip/hip_runtime.h>

// MetricBiasUpdater: B_next = clip(alpha*B_prev - beta*relu(pairdist(H@W^T)), -10, 10)
// B=4, N=2048, D=1024, K(geom)=32. Output fp32 [4,2048,2048].
//
// v5:
//  k0: W fp32 -> bf16 once.
//  k1: unchanged (LDS-staged H, MFMA).
//  k2: SAME structure as v4 (LDS-free, barrier-free) but the load schedule
//      is PINNED. v2-v4 all compiled to VGPR=36 -- the backend sank every
//      "prefetched" load to its use, serializing 8 HBM round-trips per wave
//      (why all three variants were stuck at ~41 us / 2.5 TB/s).
//      Now: phase 1 issues ALL loads (G frags + Q first, Bp last so the
//      MFMA vmcnt-wait keeps Bp in flight); sched_barrier(0) forbids
//      sinking; launch_bounds(256,3) lets the allocator keep them live.

typedef __attribute__((ext_vector_type(8))) short short8;   // 8 bf16 (4 VGPRs)
typedef __attribute__((ext_vector_type(4))) short short4v;  // 4 bf16 (2 VGPRs)
typedef __attribute__((ext_vector_type(4))) float floatx4;  // MFMA acc

static __device__ __forceinline__ short bf16_bits(float f) {
    union { float f; unsigned int u; } v; v.f = f;
    unsigned int u = v.u;
    u += 0x7FFFu + ((u >> 16) & 1u);   // round-to-nearest-even
    return (short)(u >> 16);
}

static __device__ __forceinline__ float bf16_to_f32(unsigned short h) {
    union { unsigned int u; float f; } v; v.u = ((unsigned int)h) << 16;
    return v.f;
}

// ---------------------------------------------------------------------------
// Kernel 0: W fp32 [32][1024] -> bf16.
// ---------------------------------------------------------------------------
__global__ __launch_bounds__(256) void k0_wcast(const float* __restrict__ W,
                                                short* __restrict__ Wb) {
    const int f = blockIdx.x * 256 + threadIdx.x;   // 8192 float4 chunks
    const float4 v = *(const float4*)(W + (long)f * 4);
    short4v s;
    s[0] = bf16_bits(v.x); s[1] = bf16_bits(v.y);
    s[2] = bf16_bits(v.z); s[3] = bf16_bits(v.w);
    *(short4v*)(Wb + (long)f * 4) = s;
}

// ---------------------------------------------------------------------------
// Kernel 1: G[row][k] = sum_d H[row][d] * W[k][d]  (rows = 8192 flat, k = 32)
// ---------------------------------------------------------------------------
__global__ __launch_bounds__(256) void k1_proj(const float* __restrict__ H,
                                               const short* __restrict__ Wb,
                                               unsigned short* __restrict__ G,
                                               float* __restrict__ Q) {
    const int blk  = blockIdx.x;        // 512 blocks x 16 rows
    const int t    = threadIdx.x;
    const int w    = t >> 6;            // wave id -> K quarter
    const int lane = t & 63;
    const int m    = lane & 15;         // A row within tile / B column n
    const int quad = lane >> 4;

    __shared__ short sH[16 * 1032];     // 16 rows x 1024 bf16, stride 1032 (33 KB)

    // ---- coalesced stage: 2048 8-float chunks, 8 per thread ----
    const float* Hb = H + (long)blk * 16384;
    #pragma unroll
    for (int it = 0; it < 8; ++it) {
        const int f  = t + it * 256;    // 0..2047
        const int r  = f >> 7;          // row 0..15
        const int c8 = f & 127;         // 8-float chunk within row
        const float4 v0 = *(const float4*)(Hb + r * 1024 + c8 * 8);
        const float4 v1 = *(const float4*)(Hb + r * 1024 + c8 * 8 + 4);
        short8 sv;
        sv[0] = bf16_bits(v0.x); sv[1] = bf16_bits(v0.y);
        sv[2] = bf16_bits(v0.z); sv[3] = bf16_bits(v0.w);
        sv[4] = bf16_bits(v1.x); sv[5] = bf16_bits(v1.y);
        sv[6] = bf16_bits(v1.z); sv[7] = bf16_bits(v1.w);
        *(short8*)&sH[r * 1032 + c8 * 8] = sv;
    }
    __syncthreads();

    const int kq = w * 256 + quad * 8;  // this lane's k base (frag: k = quad*8 + j)
    const short* wb0 = Wb + (long)m * 1024 + kq;          // n-tile 0: n = m
    const short* wb1 = Wb + (long)(m + 16) * 1024 + kq;   // n-tile 1: n = m+16

    floatx4 acc0 = {0.f, 0.f, 0.f, 0.f};
    floatx4 acc1 = {0.f, 0.f, 0.f, 0.f};

    short8 b0 = *(const short8*)wb0;
    short8 b1 = *(const short8*)wb1;

    #pragma unroll
    for (int s = 0; s < 8; ++s) {
        short8 nb0, nb1;
        if (s < 7) {                    // prefetch next W-step while MFMA runs
            nb0 = *(const short8*)(wb0 + (s + 1) * 32);
            nb1 = *(const short8*)(wb1 + (s + 1) * 32);
        }
        const short8 af = *(const short8*)&sH[m * 1032 + kq + s * 32];
        acc0 = __builtin_amdgcn_mfma_f32_16x16x32_bf16(af, b0, acc0, 0, 0, 0);
        acc1 = __builtin_amdgcn_mfma_f32_16x16x32_bf16(af, b1, acc1, 0, 0, 0);
        if (s < 7) { b0 = nb0; b1 = nb1; }
    }

    // reduce K-quarter partials across the 4 waves.
    // C/D layout: col = lane&15 (=n), row = quad*4 + reg (=m)  (measured m89)
    __shared__ float red[4][16][32];
    #pragma unroll
    for (int r = 0; r < 4; ++r) {
        red[w][quad * 4 + r][m]      = acc0[r];
        red[w][quad * 4 + r][m + 16] = acc1[r];
    }
    __syncthreads();
    for (int e = t; e < 512; e += 256) {
        const int mm = e >> 5, nn = e & 31;
        float v = red[0][mm][nn] + red[1][mm][nn] + red[2][mm][nn] + red[3][mm][nn];
        const unsigned short hb = (unsigned short)bf16_bits(v);
        G[(long)(blk * 16 + mm) * 32 + nn] = hb;
        red[0][mm][nn] = bf16_to_f32(hb);   // Q from ROUNDED values: dist(i,i) ~ 0
    }
    __syncthreads();
    if (t < 16) {
        float s = 0.f;
        #pragma unroll
        for (int nn = 0; nn < 32; ++nn) { const float v = red[0][t][nn]; s += v * v; }
        Q[blk * 16 + t] = s;
    }
}

// ---------------------------------------------------------------------------
// Kernel 2: out[b][i][j] = clip(alpha*Bp - beta*relu(q[i]+q[j]-2*G[i].G[j]))
// 64(i) x 128(j) tile per block, 4 waves, no LDS, no barriers.
// Phase 1: issue ALL loads (G frags + Q early; 8x Bp dwordx4 LAST so the
//          MFMA's vmcnt wait leaves them outstanding). sched_barrier(0).
// Phase 2: 8x mfma(Gj_frag, Gi_frag) -> D row = j (consecutive), col = i.
// Phase 3: epilogue drains bv[jt] progressively, 8x dwordx4 stores.
// ---------------------------------------------------------------------------
__global__ __launch_bounds__(256, 3) void k2_update(const float* __restrict__ Bp,
                                                    const unsigned short* __restrict__ G,
                                                    const float* __restrict__ Q,
                                                    const float* __restrict__ alphap,
                                                    const float* __restrict__ betap,
                                                    float* __restrict__ out) {
    const int b  = blockIdx.z;
    const int i0 = blockIdx.y * 64;
    const int j0 = blockIdx.x * 128;
    const int t  = threadIdx.x;
    const int w    = t >> 6;          // wave -> i rows [w*16, w*16+16)
    const int lane = t & 63;
    const int m    = lane & 15;       // i within wave tile (D column)
    const int quad = lane >> 4;       // j sub-quad (D row group)

    const int i = i0 + w * 16 + m;
    const long rowoff = ((long)b * 2048 + i) * 2048 + j0;

    // ================= phase 1: issue everything =================
    const float alpha = alphap[0];
    const float beta  = betap[0];
    const float qi = Q[b * 2048 + i];

    const short* Gg = (const short*)G;
    // B-frag (index = i): lane holds Gi row w*16+m, bytes [quad*16, quad*16+16)
    const short8 bfi = *(const short8*)&Gg[((long)(b * 2048 + i0 + w * 16 + m)) * 32 + quad * 8];
    // A-frags (index = j): lane holds Gj row jt*16+m, same k slice (1KB contig/frag)
    short8 afj[8];
    const long gj_base = ((long)(b * 2048 + j0 + m)) * 32 + quad * 8;
    #pragma unroll
    for (int jt = 0; jt < 8; ++jt)
        afj[jt] = *(const short8*)&Gg[gj_base + (long)jt * 16 * 32];

    // Q[j] values for the epilogue (L2-resident)
    float4 qjv[8];
    #pragma unroll
    for (int jt = 0; jt < 8; ++jt)
        qjv[jt] = *(const float4*)&Q[b * 2048 + j0 + jt * 16 + quad * 4];

    // Bp: HBM, issued LAST -> stays in flight through the MFMA phase
    float4 bv[8];
    const float4* bp4 = (const float4*)(Bp + rowoff);
    #pragma unroll
    for (int jt = 0; jt < 8; ++jt) bv[jt] = bp4[jt * 4 + quad];  // j = jt*16+quad*4

    __builtin_amdgcn_sched_barrier(0);   // nothing moves across: loads stay issued

    // ================= phase 2: MFMA =================
    floatx4 acc[8];
    #pragma unroll
    for (int jt = 0; jt < 8; ++jt) {
        floatx4 z = {0.f, 0.f, 0.f, 0.f};
        acc[jt] = __builtin_amdgcn_mfma_f32_16x16x32_bf16(afj[jt], bfi, z, 0, 0, 0);
    }

    // ================= phase 3: fused epilogue =================
    float4* o4 = (float4*)(out + rowoff);
    #pragma unroll
    for (int jt = 0; jt < 8; ++jt) {
        // D layout: row = quad*4 + r = j within tile jt, col = m = i
        const float4 qj = qjv[jt];
        const float4 bb = bv[jt];
        float4 ov;
        {
            float d = qi + qj.x - 2.f * acc[jt][0];
            d = fmaxf(d, 0.f);
            ov.x = fminf(fmaxf(alpha * bb.x - beta * d, -10.f), 10.f);
        }
        {
            float d = qi + qj.y - 2.f * acc[jt][1];
            d = fmaxf(d, 0.f);
            ov.y = fminf(fmaxf(alpha * bb.y - beta * d, -10.f), 10.f);
        }
        {
            float d = qi + qj.z - 2.f * acc[jt][2];
            d = fmaxf(d, 0.f);
            ov.z = fminf(fmaxf(alpha * bb.z - beta * d, -10.f), 10.f);
        }
        {
            float d = qi + qj.w - 2.f * acc[jt][3];
            d = fmaxf(d, 0.f);
            ov.w = fminf(fmaxf(alpha * bb.w - beta * d, -10.f), 10.f);
        }
        o4[jt * 4 + quad] = ov;
    }
}

extern "C" void kernel_launch(void* const* d_in, const int* in_sizes, int n_in,
                              void* d_out, int out_size, void* d_ws, size_t ws_size,
                              hipStream_t stream) {
    const float* H     = (const float*)d_in[0];   // [4,2048,1024]
    const float* Bp    = (const float*)d_in[1];   // [4,2048,2048]
    const float* W     = (const float*)d_in[2];   // [32,1024]
    const float* alpha = (const float*)d_in[3];
    const float* beta  = (const float*)d_in[4];
    float* out = (float*)d_out;

    unsigned short* G = (unsigned short*)d_ws;          // [8192][32] bf16 = 512 KB
    float* Q  = (float*)((char*)d_ws + 8192 * 32 * 2);  // [8192] fp32 = 32 KB
    short* Wb = (short*)((char*)d_ws + 8192 * 32 * 2 + 8192 * 4);  // [32][1024] bf16

    k0_wcast<<<32, 256, 0, stream>>>(W, Wb);
    k1_proj<<<512, 256, 0, stream>>>(H, Wb, G, Q);

    dim3 g2(16, 32, 4);               // j-tiles(128), i-tiles(64), batch
    k2_update<<<g2, 256, 0, stream>>>(Bp, G, Q, alpha, beta, out);
}